// Round 1
// 8469.709 us; speedup vs baseline: 1.0424x; 1.0424x over previous
//
#include <hip/hip_runtime.h>

// Seq2SeqLSTM: B=32, T=128, E=512, H=1024, V=32000
// R1: persistent lstm_scan kernels (Whh bf16 in VGPRs, MFMA recurrence,
//     device-scope grid barrier per step).
// R2: pipeline the two layers of each stack into ONE persistent kernel
//     (layer0 computes t=s while layer1 computes t=s-1). Grid-barrier links
//     in the serial chain drop 512 -> 258; layer1's input projection is
//     computed on the fly (Wih1 slice in LDS, XOR-swizzled). Removes the
//     two xg GEMMs for layer-1 inputs and all hseq writes except dec layer1.

#define TSEQ  128
#define NB    32
#define EMB   512
#define HID   1024
#define G4    4096
#define VOC   32000
#define ROWS  (TSEQ * NB)   /* 4096 */
#define SCAN_BLOCKS 128

typedef __attribute__((ext_vector_type(8))) short short8;   // 8 bf16 (4 VGPRs)
typedef __attribute__((ext_vector_type(4))) float f32x4;    // MFMA acc

__device__ __forceinline__ unsigned short f2bf(float f) {
  unsigned u = __builtin_bit_cast(unsigned, f);
  u += 0x7FFFu + ((u >> 16) & 1u);            // RNE
  return (unsigned short)(u >> 16);
}

__device__ __forceinline__ short8 pack8(float4 a, float4 b) {
  short8 v;
  v[0] = (short)f2bf(a.x); v[1] = (short)f2bf(a.y);
  v[2] = (short)f2bf(a.z); v[3] = (short)f2bf(a.w);
  v[4] = (short)f2bf(b.x); v[5] = (short)f2bf(b.y);
  v[6] = (short)f2bf(b.z); v[7] = (short)f2bf(b.w);
  return v;
}

__device__ __forceinline__ float fsig(float x)  { return 1.f / (1.f + __expf(-x)); }
__device__ __forceinline__ float ftanh(float x) { return 1.f - 2.f / (1.f + __expf(2.f * x)); }

__device__ __forceinline__ void async16(const void* g, void* l) {
  __builtin_amdgcn_global_load_lds((const __attribute__((address_space(1))) void*)g,
                                   (__attribute__((address_space(3))) void*)l, 16, 0, 0);
}

// ---------------- fp32 -> bf16 bulk convert ----------------
__global__ __launch_bounds__(256) void cvt_bf16(const float* __restrict__ src,
                                                unsigned short* __restrict__ dst, int n) {
  int i = (blockIdx.x * 256 + threadIdx.x) * 8;
  if (i >= n) return;
  float4 a = *(const float4*)&src[i];
  float4 b = *(const float4*)&src[i + 4];
  *(ushort4*)&dst[i]     = make_ushort4(f2bf(a.x), f2bf(a.y), f2bf(a.z), f2bf(a.w));
  *(ushort4*)&dst[i + 4] = make_ushort4(f2bf(b.x), f2bf(b.y), f2bf(b.z), f2bf(b.w));
}

// ---------------- embedding gather -> bf16 [T*B, E] (row = t*B+b) ----------------
__global__ __launch_bounds__(256) void gather_embed(const int* __restrict__ tok,
                                                    const float* __restrict__ emb,
                                                    unsigned short* __restrict__ dst, int dec) {
  int idx = blockIdx.x * 256 + threadIdx.x;   // one float4 per thread over [4096][512]
  int n = idx >> 7;                           // row (EMB/4 = 128 chunks per row)
  int e = (idx & 127) * 4;
  int t = n >> 5, b = n & 31;
  int token;
  if (dec) token = (t == 0) ? 0 : tok[b * TSEQ + t - 1];
  else     token = tok[b * TSEQ + t];
  float4 v = *(const float4*)&emb[(size_t)token * EMB + e];
  *(ushort4*)&dst[(size_t)n * EMB + e] = make_ushort4(f2bf(v.x), f2bf(v.y), f2bf(v.z), f2bf(v.w));
}

// ---------------- zero fill ----------------
__global__ __launch_bounds__(256) void zero_f(float* __restrict__ p, int n4) {
  for (int i = blockIdx.x * 256 + threadIdx.x; i < n4; i += gridDim.x * 256)
    ((float4*)p)[i] = make_float4(0.f, 0.f, 0.f, 0.f);
}

// ---------------- bf16 MFMA GEMM: C[M,N] = A[M,K] * B[N,K]^T + bias[N] ----------------
// mode 0: C[row*N+col]   (proj -> x_gates)
// mode 1: C[(b*TSEQ+t)*N+col], row = t*NB+b  (logits scatter to [B,T,V])
__global__ __launch_bounds__(256)
void gemm_bt(const unsigned short* __restrict__ A, const unsigned short* __restrict__ B,
             float* __restrict__ C, const float* __restrict__ bias,
             int M, int N, int K, int mode) {
  __shared__ short As[128 * 32];
  __shared__ short Bs[128 * 32];
  const int tid  = threadIdx.x;
  const int lane = tid & 63;
  const int wave = tid >> 6;
  const int m0 = blockIdx.y * 128, n0 = blockIdx.x * 128;
  const int wm = (wave >> 1) * 64, wn = (wave & 1) * 64;
  const int r = lane & 15, q = lane >> 4;

  f32x4 acc[4][4];
#pragma unroll
  for (int i = 0; i < 4; ++i)
#pragma unroll
    for (int j = 0; j < 4; ++j) acc[i][j] = (f32x4){0.f, 0.f, 0.f, 0.f};

  const int srow = tid >> 2;         // 0..63
  const int scol = (tid & 3) * 8;    // 0,8,16,24

  for (int k0 = 0; k0 < K; k0 += 32) {
    async16(&A[(size_t)(m0 + srow) * K + k0 + scol],      &As[tid * 8]);
    async16(&A[(size_t)(m0 + 64 + srow) * K + k0 + scol], &As[2048 + tid * 8]);
    async16(&B[(size_t)(n0 + srow) * K + k0 + scol],      &Bs[tid * 8]);
    async16(&B[(size_t)(n0 + 64 + srow) * K + k0 + scol], &Bs[2048 + tid * 8]);
    __builtin_amdgcn_s_waitcnt(0);
    __syncthreads();

    short8 af[4], bfr[4];
#pragma unroll
    for (int tm = 0; tm < 4; ++tm)
      af[tm] = *(const short8*)&As[(wm + tm * 16 + r) * 32 + q * 8];
#pragma unroll
    for (int tn = 0; tn < 4; ++tn)
      bfr[tn] = *(const short8*)&Bs[(wn + tn * 16 + r) * 32 + q * 8];
#pragma unroll
    for (int tm = 0; tm < 4; ++tm)
#pragma unroll
      for (int tn = 0; tn < 4; ++tn)
        acc[tm][tn] = __builtin_amdgcn_mfma_f32_16x16x32_bf16(af[tm], bfr[tn], acc[tm][tn], 0, 0, 0);
    __syncthreads();
  }

#pragma unroll
  for (int tm = 0; tm < 4; ++tm) {
#pragma unroll
    for (int tn = 0; tn < 4; ++tn) {
      f32x4 v = acc[tm][tn];
      int col = n0 + wn + tn * 16 + r;
      float bv = bias[col];
#pragma unroll
      for (int e = 0; e < 4; ++e) {
        int row = m0 + wm + tm * 16 + q * 4 + e;
        float val = v[e] + bv;
        size_t oidx;
        if (mode == 0) {
          oidx = (size_t)row * N + col;
        } else {
          int tt = row >> 5, bb = row & 31;
          oidx = (size_t)(bb * TSEQ + tt) * N + col;
        }
        C[oidx] = val;
      }
    }
  }
}

// ---------------- persistent 2-layer pipelined LSTM scan ----------------
// 128 blocks x 256 threads. Block j owns h-dims [j*8, j*8+8) for BOTH layers
// (32 gate rows each). Whh0/Whh1 slices (bf16) live in VGPRs (256 regs);
// Wih1 slice (32 rows x 1024 bf16 = 64 KB) lives in LDS (XOR-swizzled 16B
// chunks: c16 ^ (row&7), so stride-2048B fragment reads are ~conflict-free).
// Pipeline: at step s, layer0 computes t=s (s<128), layer1 computes t=s-1
// (s>=1) using layer0's ping-pong h buffer directly. 129 steps, ONE grid
// barrier per step (skipped on the last) -> 128 barrier links per launch.
__global__ __launch_bounds__(256, 1)
void lstm_scan2(const float* __restrict__ Whh0, const float* __restrict__ Whh1,
                const unsigned short* __restrict__ Wih1,  // bf16 [4096][1024]
                const float* __restrict__ b1,
                const float* __restrict__ xg,             // layer0 x-gates [T*B][4096]
                unsigned short* __restrict__ h0A, unsigned short* __restrict__ h0B,
                float* __restrict__ c0buf,
                unsigned short* __restrict__ h1A, unsigned short* __restrict__ h1B,
                float* __restrict__ c1buf,
                unsigned short* __restrict__ hseq1, int write_seq,
                unsigned* __restrict__ bar) {
  __shared__ float Gs0[32][33];
  __shared__ float Gs1[32][33];
  __shared__ unsigned short Wlds[32 * 1024];   // 64 KB, swizzled
  const int tid  = threadIdx.x;
  const int lane = tid & 63;
  const int wave = tid >> 6;
  const int r = lane & 15, q = lane >> 4;
  const int mt = wave >> 1, nt = wave & 1;
  const int D0 = blockIdx.x * 8;

  // --- Whh0/Whh1 B-fragments into VGPRs (bf16): 16 rows x 1024 K per wave
  const int lr   = nt * 16 + r;                         // local gate-row 0..31
  const int grow = (lr >> 3) * HID + D0 + (lr & 7);     // global gate-row
  short8 Bf0[32], Bf1[32];
  {
    const float* wp0 = &Whh0[(size_t)grow * HID];
    const float* wp1 = &Whh1[(size_t)grow * HID];
#pragma unroll
    for (int ks = 0; ks < 32; ++ks) {
      Bf0[ks] = pack8(*(const float4*)&wp0[ks * 32 + q * 8],
                      *(const float4*)&wp0[ks * 32 + q * 8 + 4]);
      Bf1[ks] = pack8(*(const float4*)&wp1[ks * 32 + q * 8],
                      *(const float4*)&wp1[ks * 32 + q * 8 + 4]);
    }
  }

  // --- stage Wih1 slice into LDS, XOR-swizzled 16B chunks
#pragma unroll
  for (int i = 0; i < 16; ++i) {
    int j   = i * 256 + tid;
    int lr2 = j >> 7, c16 = j & 127;
    int gr2 = (lr2 >> 3) * HID + D0 + (lr2 & 7);
    short8 v = *(const short8*)&Wih1[(size_t)gr2 * HID + c16 * 8];
    *(short8*)((char*)Wlds + lr2 * 2048 + ((c16 ^ (lr2 & 7)) * 16)) = v;
  }

  // --- per-thread cell state + layer1 bias: thread -> (b = tid>>3, d = tid&7)
  const int cd = tid & 7, cb = tid >> 3;
  float creg0 = c0buf[cb * HID + D0 + cd];
  float creg1 = c1buf[cb * HID + D0 + cd];
  const float bi1 = b1[0 * HID + D0 + cd];
  const float bf1 = b1[1 * HID + D0 + cd];
  const float bg1 = b1[2 * HID + D0 + cd];
  const float bo1 = b1[3 * HID + D0 + cd];
  __syncthreads();

  for (int s = 0; s <= TSEQ; ++s) {
    const int t0c = (s < TSEQ) ? s : (TSEQ - 1);   // clamped (edge steps run
    const int t1c = (s >= 1) ? (s - 1) : 0;        //  MFMA on stale-but-finite data)

    // prefetch layer0 x-gates for this thread's cell (hide HBM latency)
    const float* xrow = &xg[((size_t)t0c * NB + cb) * G4 + D0 + cd];
    const float x_i = xrow[0];
    const float x_f = xrow[HID];
    const float x_g = xrow[2 * HID];
    const float x_o = xrow[3 * HID];

    // --- layer0: G0 = h0_prev @ Whh0_slice^T
    {
      const unsigned short* h0in = (t0c & 1) ? h0B : h0A;
      const unsigned short* hrow = &h0in[(size_t)(mt * 16 + r) * HID + q * 8];
      f32x4 a0 = (f32x4){0.f, 0.f, 0.f, 0.f}, a1 = a0, a2 = a0, a3 = a0;
#pragma unroll
      for (int ks = 0; ks < 32; ks += 4) {
        a0 = __builtin_amdgcn_mfma_f32_16x16x32_bf16(*(const short8*)&hrow[(ks + 0) * 32], Bf0[ks + 0], a0, 0, 0, 0);
        a1 = __builtin_amdgcn_mfma_f32_16x16x32_bf16(*(const short8*)&hrow[(ks + 1) * 32], Bf0[ks + 1], a1, 0, 0, 0);
        a2 = __builtin_amdgcn_mfma_f32_16x16x32_bf16(*(const short8*)&hrow[(ks + 2) * 32], Bf0[ks + 2], a2, 0, 0, 0);
        a3 = __builtin_amdgcn_mfma_f32_16x16x32_bf16(*(const short8*)&hrow[(ks + 3) * 32], Bf0[ks + 3], a3, 0, 0, 0);
      }
      f32x4 acc = (a0 + a1) + (a2 + a3);
#pragma unroll
      for (int e = 0; e < 4; ++e)
        Gs0[mt * 16 + q * 4 + e][nt * 16 + r] = acc[e];
    }

    // --- layer1: G1 = h1_prev @ Whh1_slice^T + h0[t1] @ Wih1_slice^T
    {
      const unsigned short* h1in = (t1c & 1) ? h1B : h1A;         // h1[t1-1]
      const unsigned short* h0t  = (t1c & 1) ? h0A : h0B;         // h0[t1]
      const unsigned short* hrow1 = &h1in[(size_t)(mt * 16 + r) * HID + q * 8];
      const unsigned short* hrowx = &h0t [(size_t)(mt * 16 + r) * HID + q * 8];
      f32x4 a0 = (f32x4){0.f, 0.f, 0.f, 0.f}, a1 = a0, a2 = a0, a3 = a0;
#pragma unroll
      for (int ks = 0; ks < 32; ks += 4) {
        a0 = __builtin_amdgcn_mfma_f32_16x16x32_bf16(*(const short8*)&hrow1[(ks + 0) * 32], Bf1[ks + 0], a0, 0, 0, 0);
        a1 = __builtin_amdgcn_mfma_f32_16x16x32_bf16(*(const short8*)&hrow1[(ks + 1) * 32], Bf1[ks + 1], a1, 0, 0, 0);
        a2 = __builtin_amdgcn_mfma_f32_16x16x32_bf16(*(const short8*)&hrow1[(ks + 2) * 32], Bf1[ks + 2], a2, 0, 0, 0);
        a3 = __builtin_amdgcn_mfma_f32_16x16x32_bf16(*(const short8*)&hrow1[(ks + 3) * 32], Bf1[ks + 3], a3, 0, 0, 0);
      }
#pragma unroll
      for (int ks = 0; ks < 32; ks += 4) {
        short8 w0 = *(const short8*)((const char*)Wlds + lr * 2048 + ((((ks + 0) * 4 + q) ^ (lr & 7)) * 16));
        short8 w1 = *(const short8*)((const char*)Wlds + lr * 2048 + ((((ks + 1) * 4 + q) ^ (lr & 7)) * 16));
        short8 w2 = *(const short8*)((const char*)Wlds + lr * 2048 + ((((ks + 2) * 4 + q) ^ (lr & 7)) * 16));
        short8 w3 = *(const short8*)((const char*)Wlds + lr * 2048 + ((((ks + 3) * 4 + q) ^ (lr & 7)) * 16));
        a0 = __builtin_amdgcn_mfma_f32_16x16x32_bf16(*(const short8*)&hrowx[(ks + 0) * 32], w0, a0, 0, 0, 0);
        a1 = __builtin_amdgcn_mfma_f32_16x16x32_bf16(*(const short8*)&hrowx[(ks + 1) * 32], w1, a1, 0, 0, 0);
        a2 = __builtin_amdgcn_mfma_f32_16x16x32_bf16(*(const short8*)&hrowx[(ks + 2) * 32], w2, a2, 0, 0, 0);
        a3 = __builtin_amdgcn_mfma_f32_16x16x32_bf16(*(const short8*)&hrowx[(ks + 3) * 32], w3, a3, 0, 0, 0);
      }
      f32x4 acc = (a0 + a1) + (a2 + a3);
#pragma unroll
      for (int e = 0; e < 4; ++e)
        Gs1[mt * 16 + q * 4 + e][nt * 16 + r] = acc[e];
    }
    __syncthreads();

    // --- layer0 cell update for (cb, cd)
    if (s < TSEQ) {
      float iv = Gs0[cb][cd]      + x_i;
      float fv = Gs0[cb][8 + cd]  + x_f;
      float gv = Gs0[cb][16 + cd] + x_g;
      float ov = Gs0[cb][24 + cd] + x_o;
      float ig = fsig(iv), fg = fsig(fv), og = fsig(ov);
      float gg = ftanh(gv);
      creg0 = fg * creg0 + ig * gg;
      float hn = og * ftanh(creg0);
      ((t0c & 1) ? h0A : h0B)[cb * HID + D0 + cd] = f2bf(hn);
    }
    // --- layer1 cell update
    if (s >= 1) {
      float iv = Gs1[cb][cd]      + bi1;
      float fv = Gs1[cb][8 + cd]  + bf1;
      float gv = Gs1[cb][16 + cd] + bg1;
      float ov = Gs1[cb][24 + cd] + bo1;
      float ig = fsig(iv), fg = fsig(fv), og = fsig(ov);
      float gg = ftanh(gv);
      creg1 = fg * creg1 + ig * gg;
      float hn = og * ftanh(creg1);
      unsigned short hb = f2bf(hn);
      ((t1c & 1) ? h1A : h1B)[cb * HID + D0 + cd] = hb;
      if (write_seq) hseq1[((size_t)t1c * NB + cb) * HID + D0 + cd] = hb;
    }

    // --- device-scope grid barrier (skipped after the final step)
    if (s < TSEQ) {
      __syncthreads();
      if (tid == 0) {
        __threadfence();
        atomicAdd(bar, 1u);
        const unsigned target = (unsigned)(s + 1) * SCAN_BLOCKS;
        while (__hip_atomic_load(bar, __ATOMIC_RELAXED, __HIP_MEMORY_SCOPE_AGENT) < target)
          __builtin_amdgcn_s_sleep(2);
        __threadfence();
      }
      __syncthreads();
    }
  }
  c0buf[cb * HID + D0 + cd] = creg0;   // finals (decoder init)
  c1buf[cb * HID + D0 + cd] = creg1;
}

// ---------------- in-place log_softmax over V per row ----------------
__global__ __launch_bounds__(256) void logsoftmax_rows(float* __restrict__ out) {
  __shared__ float red[256];
  float* p = out + (size_t)blockIdx.x * VOC;
  const int tid = threadIdx.x;
  float m = -3.4e38f;
  for (int i = tid; i < VOC / 4; i += 256) {
    float4 v = ((const float4*)p)[i];
    m = fmaxf(m, fmaxf(fmaxf(v.x, v.y), fmaxf(v.z, v.w)));
  }
  red[tid] = m; __syncthreads();
  for (int s = 128; s; s >>= 1) { if (tid < s) red[tid] = fmaxf(red[tid], red[tid + s]); __syncthreads(); }
  float M = red[0]; __syncthreads();
  float sum = 0.f;
  for (int i = tid; i < VOC / 4; i += 256) {
    float4 v = ((const float4*)p)[i];
    sum += __expf(v.x - M) + __expf(v.y - M) + __expf(v.z - M) + __expf(v.w - M);
  }
  red[tid] = sum; __syncthreads();
  for (int s = 128; s; s >>= 1) { if (tid < s) red[tid] += red[tid + s]; __syncthreads(); }
  float L = M + logf(red[0]); __syncthreads();
  for (int i = tid; i < VOC / 4; i += 256) {
    float4 v = ((const float4*)p)[i];
    v.x -= L; v.y -= L; v.z -= L; v.w -= L;
    ((float4*)p)[i] = v;
  }
}

extern "C" void kernel_launch(void* const* d_in, const int* in_sizes, int n_in,
                              void* d_out, int out_size, void* d_ws, size_t ws_size,
                              hipStream_t stream) {
  const int*   x     = (const int*)  d_in[0];
  const int*   tgt   = (const int*)  d_in[1];
  const float* emb   = (const float*)d_in[2];
  const float* eWih0 = (const float*)d_in[3];
  const float* eWhh0 = (const float*)d_in[4];
  const float* eb0   = (const float*)d_in[5];
  const float* eWih1 = (const float*)d_in[6];
  const float* eWhh1 = (const float*)d_in[7];
  const float* eb1   = (const float*)d_in[8];
  const float* dWih0 = (const float*)d_in[9];
  const float* dWhh0 = (const float*)d_in[10];
  const float* db0   = (const float*)d_in[11];
  const float* dWih1 = (const float*)d_in[12];
  const float* dWhh1 = (const float*)d_in[13];
  const float* db1   = (const float*)d_in[14];
  const float* fcW   = (const float*)d_in[15];
  const float* fcb   = (const float*)d_in[16];
  float* out = (float*)d_out;

  char* base = (char*)d_ws;
  size_t off = 0;
  auto carve = [&](size_t bytes) -> void* {
    void* p = base + off;
    off += (bytes + 255) & ~(size_t)255;
    return p;
  };
  unsigned short* wE0   = (unsigned short*)carve((size_t)G4 * EMB * 2);
  unsigned short* wE1   = (unsigned short*)carve((size_t)G4 * HID * 2);
  unsigned short* wD0   = (unsigned short*)carve((size_t)G4 * EMB * 2);
  unsigned short* wD1   = (unsigned short*)carve((size_t)G4 * HID * 2);
  unsigned short* wFC   = (unsigned short*)carve((size_t)VOC * HID * 2);
  unsigned short* encin = (unsigned short*)carve((size_t)ROWS * EMB * 2);
  unsigned short* decin = (unsigned short*)carve((size_t)ROWS * EMB * 2);
  unsigned short* seqB  = (unsigned short*)carve((size_t)ROWS * HID * 2);
  float* xg = (float*)carve((size_t)ROWS * G4 * 4);
  // zero-region (contiguous, all sizes multiple of 256B):
  unsigned short* hA0 = (unsigned short*)carve((size_t)NB * HID * 2);
  unsigned short* hB0 = (unsigned short*)carve((size_t)NB * HID * 2);
  unsigned short* hA1 = (unsigned short*)carve((size_t)NB * HID * 2);
  unsigned short* hB1 = (unsigned short*)carve((size_t)NB * HID * 2);
  float* c0 = (float*)carve((size_t)NB * HID * 4);
  float* c1 = (float*)carve((size_t)NB * HID * 4);
  unsigned* bars = (unsigned*)carve(1024);
  const int zero_n4 = (4 * NB * HID * 2 + 2 * NB * HID * 4 + 1024) / 16;

  // weights -> bf16
  cvt_bf16<<<dim3(G4 * EMB / 2048), 256, 0, stream>>>(eWih0, wE0, G4 * EMB);
  cvt_bf16<<<dim3(G4 * HID / 2048), 256, 0, stream>>>(eWih1, wE1, G4 * HID);
  cvt_bf16<<<dim3(G4 * EMB / 2048), 256, 0, stream>>>(dWih0, wD0, G4 * EMB);
  cvt_bf16<<<dim3(G4 * HID / 2048), 256, 0, stream>>>(dWih1, wD1, G4 * HID);
  cvt_bf16<<<dim3(VOC * HID / 2048), 256, 0, stream>>>(fcW, wFC, VOC * HID);
  // embeddings
  gather_embed<<<dim3(ROWS * EMB / 1024), 256, 0, stream>>>(x, emb, encin, 0);
  gather_embed<<<dim3(ROWS * EMB / 1024), 256, 0, stream>>>(tgt, emb, decin, 1);
  // zero h/c/barrier region
  zero_f<<<dim3(128), 256, 0, stream>>>((float*)hA0, zero_n4);

  // ---- encoder: layer0 x-gates GEMM, then pipelined 2-layer scan ----
  gemm_bt<<<dim3(G4 / 128, ROWS / 128), 256, 0, stream>>>(encin, wE0, xg, eb0, ROWS, G4, EMB, 0);
  lstm_scan2<<<dim3(SCAN_BLOCKS), 256, 0, stream>>>(eWhh0, eWhh1, wE1, eb1, xg,
                                                    hA0, hB0, c0, hA1, hB1, c1,
                                                    seqB, 0, bars + 0);
  // ---- decoder: continues from encoder finals (h in A-slots, c in cbufs) ----
  gemm_bt<<<dim3(G4 / 128, ROWS / 128), 256, 0, stream>>>(decin, wD0, xg, db0, ROWS, G4, EMB, 0);
  lstm_scan2<<<dim3(SCAN_BLOCKS), 256, 0, stream>>>(dWhh0, dWhh1, wD1, db1, xg,
                                                    hA0, hB0, c0, hA1, hB1, c1,
                                                    seqB, 1, bars + 16);
  // ---- logits + log_softmax ----
  gemm_bt<<<dim3(VOC / 128, ROWS / 128), 256, 0, stream>>>(seqB, wFC, out, fcb, ROWS, VOC, HID, 1);
  logsoftmax_rows<<<dim3(ROWS), 256, 0, stream>>>(out);
}